// Round 9
// baseline (415.470 us; speedup 1.0000x reference)
//
#include <hip/hip_runtime.h>
#include <hip/hip_bf16.h>

// Haar wavelet transform: x (16,64,512,512) f32 -> 4 planes (16,64,256,256) f32.
//
// R9: R8 (one-shot blocks, wave-per-plane writes; 396us) scaled 4x in stream
// run length. 1024-thread block covers 16 output rows (4 row-groups) of one
// channel: reads 64KB contiguous input, each plane written as 16KB contiguous
// (4 waves x 4KB). Tests whether DRAM frontier-switch amortization is the
// remaining 16% gap to the copy ceiling.
//
// Phase A: wave w (0..15) loads input row pair (2w, 2w+1) of the block's
//          32-row window (4KB contiguous per wave), butterfly -> LDS.
// Phase B: wave w writes plane (w>>2), rows (w&3)*4 .. +3 (rotated), i.e.
//          4KB per wave, 16KB contiguous per plane per block.

#define B_ 16
#define C_ 64
#define H_ 512
#define W_ 512
#define HO (H_/2)
#define WO (W_/2)
#define NPLANE (B_*C_*HO*WO)     // 67,108,864 elements per plane

typedef float f32x4 __attribute__((ext_vector_type(4)));
typedef float f32x2 __attribute__((ext_vector_type(2)));

__global__ __launch_bounds__(1024) void haar_kernel(const float* __restrict__ x,
                                                    float* __restrict__ out) {
    __shared__ float lds[16][4][256];    // [out_row_in_tile][plane][col] = 64KB
    const int w    = threadIdx.x >> 6;   // wave id 0..15
    const int lane = threadIdx.x & 63;

    const int t   = (int)blockIdx.x;     // tile id 0..16383
    const int bc  = t >> 4;              // channel 0..1023
    const int r16 = t & 15;              // 16-row group 0..15

    // ---- Phase A: dense 4KB-contiguous load per wave + butterfly -> LDS ----
    const float* in_row = x + (size_t)bc * (H_ * W_)
                            + (size_t)(r16 * 32 + 2 * w) * W_ + 4 * lane;
    const f32x4 r0a = *reinterpret_cast<const f32x4*>(in_row);
    const f32x4 r0b = *reinterpret_cast<const f32x4*>(in_row + 256);
    const f32x4 r1a = *reinterpret_cast<const f32x4*>(in_row + W_);
    const f32x4 r1b = *reinterpret_cast<const f32x4*>(in_row + W_ + 256);

    f32x2 ll_a, lh_a, hl_a, hh_a, ll_b, lh_b, hl_b, hh_b;
    {
        float p0 = r0a[0] + r0a[1], q0 = r0a[0] - r0a[1];
        float r0 = r1a[0] + r1a[1], s0 = r1a[0] - r1a[1];
        ll_a[0] = (p0 + r0) * 0.5f; hl_a[0] = (p0 - r0) * 0.5f;
        lh_a[0] = (q0 + s0) * 0.5f; hh_a[0] = (q0 - s0) * 0.5f;
        float p1 = r0a[2] + r0a[3], q1 = r0a[2] - r0a[3];
        float r1 = r1a[2] + r1a[3], s1 = r1a[2] - r1a[3];
        ll_a[1] = (p1 + r1) * 0.5f; hl_a[1] = (p1 - r1) * 0.5f;
        lh_a[1] = (q1 + s1) * 0.5f; hh_a[1] = (q1 - s1) * 0.5f;
    }
    {
        float p0 = r0b[0] + r0b[1], q0 = r0b[0] - r0b[1];
        float r0 = r1b[0] + r1b[1], s0 = r1b[0] - r1b[1];
        ll_b[0] = (p0 + r0) * 0.5f; hl_b[0] = (p0 - r0) * 0.5f;
        lh_b[0] = (q0 + s0) * 0.5f; hh_b[0] = (q0 - s0) * 0.5f;
        float p1 = r0b[2] + r0b[3], q1 = r0b[2] - r0b[3];
        float r1 = r1b[2] + r1b[3], s1 = r1b[2] - r1b[3];
        ll_b[1] = (p1 + r1) * 0.5f; hl_b[1] = (p1 - r1) * 0.5f;
        lh_b[1] = (q1 + s1) * 0.5f; hh_b[1] = (q1 - s1) * 0.5f;
    }

    *reinterpret_cast<f32x2*>(&lds[w][0][2 * lane])       = ll_a;
    *reinterpret_cast<f32x2*>(&lds[w][0][128 + 2 * lane]) = ll_b;
    *reinterpret_cast<f32x2*>(&lds[w][1][2 * lane])       = lh_a;
    *reinterpret_cast<f32x2*>(&lds[w][1][128 + 2 * lane]) = lh_b;
    *reinterpret_cast<f32x2*>(&lds[w][2][2 * lane])       = hl_a;
    *reinterpret_cast<f32x2*>(&lds[w][2][128 + 2 * lane]) = hl_b;
    *reinterpret_cast<f32x2*>(&lds[w][3][2 * lane])       = hh_a;
    *reinterpret_cast<f32x2*>(&lds[w][3][128 + 2 * lane]) = hh_b;

    __syncthreads();

    // ---- Phase B: wave w writes plane w>>2, its 4 rows rotated ----
    const int p     = w >> 2;            // plane 0..3
    const int rbase = (w & 3) * 4;       // first row of this wave's 4-row chunk
    float* plane_base = out + (size_t)p * NPLANE + (size_t)bc * (HO * WO)
                            + (size_t)(r16 * 16) * WO + 4 * lane;
#pragma unroll
    for (int s = 0; s < 4; ++s) {
        const int r = rbase + ((s + w) & 3);
        const f32x4 v = *reinterpret_cast<const f32x4*>(&lds[r][p][4 * lane]);
        *reinterpret_cast<f32x4*>(plane_base + (size_t)r * WO) = v;
    }
}

extern "C" void kernel_launch(void* const* d_in, const int* in_sizes, int n_in,
                              void* d_out, int out_size, void* d_ws, size_t ws_size,
                              hipStream_t stream) {
    const float* x = (const float*)d_in[0];
    float* out = (float*)d_out;
    haar_kernel<<<16384, 1024, 0, stream>>>(x, out);
}